// Round 10
// baseline (299.378 us; speedup 1.0000x reference)
//
#include <hip/hip_runtime.h>
#include <stdint.h>

typedef unsigned short U16;
typedef unsigned int   U32;
typedef __attribute__((ext_vector_type(8))) short short8;   // 8 bf16 = 4 VGPRs (MFMA A/B frag)
typedef __attribute__((ext_vector_type(4))) float floatx4;  // MFMA C/D frag

#define HW 3136   // 56*56
#define ICS 40    // shorts per px slot (80 B): 16B-aligned, 20-dword bank stride

__device__ __forceinline__ U16 f2b(float f){
    union { float f; unsigned int i; } v; v.f = f;
    unsigned int u = (v.i + 0x7FFFu + ((v.i >> 16) & 1u)) >> 16;  // RNE
    return (U16)u;
}
// load 8 consecutive fp32, round to bf16, return as MFMA 8x-bf16 fragment
__device__ __forceinline__ short8 pack8(const float* p){
    float4 a = *reinterpret_cast<const float4*>(p);
    float4 b = *reinterpret_cast<const float4*>(p + 4);
    short8 r;
    r[0]=(short)f2b(a.x); r[1]=(short)f2b(a.y); r[2]=(short)f2b(a.z); r[3]=(short)f2b(a.w);
    r[4]=(short)f2b(b.x); r[5]=(short)f2b(b.y); r[6]=(short)f2b(b.z); r[7]=(short)f2b(b.w);
    return r;
}

// ---------------------------------------------------------------------------
// k_conv1: t1 = mask * relu(bn1(conv1x1_g(mask * x)))   (512 -> 128, G=4)
// STRIP, 512 thr / 8 waves (round-8 structure) plus:
//  - grid.x==7 special block (g==0,b==0) runs the old k_pre (w2t transpose +
//    bn fold) -> one fewer dispatch (~13us boundary saved)
//  - conv1 blocks compute their own bn1 scale/shift in-block (32 vals,
//    bitwise-identical math) so they don't depend on k_pre
//  - staging skips the x float4 load for masked cells (t1 there is exact 0)
// t1 written PX-MAJOR [px][32 oc] for conv23's b128 reads.
// bn layout (fp32): [0:128) s1 [128:256) sh1 [256:384) s2 [384:512) sh2
//                   [512:1024) s3 [1024:1536) sh3
// ---------------------------------------------------------------------------
__global__ __launch_bounds__(512) void k_conv1(const float* __restrict__ x,
        const float* __restrict__ mask, const float* __restrict__ w1,
        const float* __restrict__ w2,
        const float* g1, const float* b1, const float* m1, const float* v1,
        const float* g2, const float* b2, const float* m2, const float* v2,
        const float* g3, const float* b3, const float* m3, const float* v3,
        U16* __restrict__ w2t, float* __restrict__ bn, U16* __restrict__ t1){
  const int t = threadIdx.x;
  const int b = blockIdx.z, g = blockIdx.y, mh = blockIdx.x;

  if (mh == 7){                              // ---- pre block (old k_pre) ----
    if ((g | b) != 0) return;
    for (int i = t; i < 4*9*32*32 + 768; i += 512){
      if (i < 4*9*32*32){
        int ic  = i & 31;
        int oc  = (i >> 5) & 31;
        int gt  = i >> 10;                   // g*9 + tap
        int g_  = gt / 9, tap = gt % 9;
        w2t[i] = f2b(w2[((g_*32 + oc)*32 + ic)*9 + tap]);
      } else {
        int j = i - 4*9*32*32;
        const float *gp, *bp, *mp, *vp; int c, so, sho;
        if (j < 128)      { c = j;       gp=g1; bp=b1; mp=m1; vp=v1; so = 0;   sho = 128;  }
        else if (j < 256) { c = j - 128; gp=g2; bp=b2; mp=m2; vp=v2; so = 256; sho = 384;  }
        else              { c = j - 256; gp=g3; bp=b3; mp=m3; vp=v3; so = 512; sho = 1024; }
        float s = gp[c] / sqrtf(vp[c] + 1e-5f);
        bn[so + c]  = s;
        bn[sho + c] = bp[c] - mp[c] * s;
      }
    }
    return;
  }

  const int lane = t & 63, wave = t >> 6;    // wave 0..7
  const int quad = lane >> 4, l15 = lane & 15;
  const int oct = wave & 1, pxq = wave >> 1; // oct 0..1, px-quarter 0..3
  const int h0 = mh*8, wbase = pxq*112;
  __shared__ float mk[7];
  __shared__ float bnl[64];                  // in-block bn1: [0:32) sc [32:64) sh
  __shared__ __align__(16) U16 xs[32*460];
  if (t < 7) mk[t] = mask[((b*4 + g)*7 + mh)*7 + t];
  if (t < 32){
    int c = g*32 + t;
    float s = g1[c] / sqrtf(v1[c] + 1e-5f);  // same math as k_pre -> same bits
    bnl[t]      = s;
    bnl[32 + t] = b1[c] - m1[c] * s;
  }
  const float* xg = x + (size_t)(b*512 + g*128)*HW + h0*56;
  U16* t1g = t1 + ((size_t)(b*4 + g)*HW + h0*56)*32;   // px-major plane

  // A fragments: w1 fp32 [oc(g*32..)][ic 128]; this wave's oct only
  const float* wg = w1 + (size_t)(g*32)*128;
  short8 afr[4];
  #pragma unroll
  for (int ks = 0; ks < 4; ++ks)
    afr[ks] = pack8(wg + (oct*16 + l15)*128 + ks*32 + quad*8);

  floatx4 acc[7] = {};
  #pragma unroll
  for (int ch = 0; ch < 4; ++ch){
    __syncthreads();   // ch=0: guards mk/bnl; ch>0: guards xs reuse
    #pragma unroll
    for (int k = 0; k < 7; ++k){
      int idx = k*512 + t;                 // 3584 float4 = 32 ic x 112
      int ic = idx / 112, f = idx - ic*112;
      int px = f*4;                        // 4 cols, never crosses an 8-col cell
      float m = mk[(px % 56) >> 3];
      uint2 pk = make_uint2(0u, 0u);
      if (m != 0.0f){                      // masked cell: skip load, exact 0
        float4 v = *reinterpret_cast<const float4*>(xg + (size_t)(ch*32 + ic)*HW + px);
        pk.x = (U32)f2b(v.x*m) | ((U32)f2b(v.y*m) << 16);
        pk.y = (U32)f2b(v.z*m) | ((U32)f2b(v.w*m) << 16);
      }
      *reinterpret_cast<uint2*>(&xs[ic*460 + px]) = pk;
    }
    __syncthreads();
    #pragma unroll
    for (int pxt = 0; pxt < 7; ++pxt){
      short8 bfr;
      #pragma unroll
      for (int j = 0; j < 8; ++j)
        bfr[j] = (short)xs[(quad*8 + j)*460 + wbase + pxt*16 + l15];
      acc[pxt] = __builtin_amdgcn_mfma_f32_16x16x32_bf16(afr[ch], bfr, acc[pxt], 0,0,0);
    }
  }
  const float* scp = bnl + oct*16 + quad*4;
  const float* shp = scp + 32;
  #pragma unroll
  for (int pxt = 0; pxt < 7; ++pxt){
    int px = wbase + pxt*16 + l15;
    float m = mk[(px % 56) >> 3];
    U16 y[4];
    #pragma unroll
    for (int reg = 0; reg < 4; ++reg)
      y[reg] = f2b(fmaxf(scp[reg]*acc[pxt][reg] + shp[reg], 0.0f) * m);  // masked: exact 0
    *reinterpret_cast<uint2*>(t1g + (size_t)px*32 + oct*16 + quad*4) =
        make_uint2((U32)y[0] | ((U32)y[1]<<16), (U32)y[2] | ((U32)y[3]<<16));
  }
}

// ---------------------------------------------------------------------------
// k_conv23: fused conv2 + conv3 for one 8x56 strip, PX-MAJOR LDS (round-8):
//   stage: t1 (px-major) 10 haloed rows -> s[10 r][58 c][ICS] (46.4 KB),
//          SKIPPING loads of masked px (t1 there is exact 0)
//   conv2: B-frag = ONE ds_read_b128 per tap; masked output cells (pxt) are
//          skipped entirely (wave-uniform branch, acc stays 0 == exact)
//   barrier; epilogue writes t2s (ALIASED into s, px-major [448][ICS])
//   barrier; conv3: b128 frag; bn3 + residual + relu -> out (nontemporal)
// ---------------------------------------------------------------------------
__global__ __launch_bounds__(512) void k_conv23(const U16* __restrict__ t1,
        const float* __restrict__ mask, const U16* __restrict__ w2t,
        const float* __restrict__ w3, const float* __restrict__ bn,
        const float* __restrict__ x, float* __restrict__ out){
  const int t = threadIdx.x;
  const int lane = t & 63, wave = t >> 6;
  const int quad = lane >> 4, l15 = lane & 15;
  const int b = blockIdx.z, g = blockIdx.y, mh = blockIdx.x;
  const int h0 = mh*8;
  __shared__ float mk[7];
  __shared__ __align__(16) U16 s[580*ICS];    // [10 r][58 c][ICS]; t2s aliases
  U16* t2s = s;                               // [448 px][ICS] (17,920 <= 23,200)
  const float* mg = mask + (b*4 + g)*49;
  if (t < 7) mk[t] = mg[mh*7 + t];
  if (t < 80){                                // zero halo col slots c=-1,56
    int si = t >> 2, part = t & 3;            // 20 slots x 4 uint4 (ic 0..31)
    int r = si >> 1, side = si & 1;
    *reinterpret_cast<uint4*>(&s[(r*58 + (side ? 57 : 0))*ICS + part*8]) =
        make_uint4(0,0,0,0);
  }
  const U16* tg = t1 + (size_t)(b*4 + g)*HW*32;   // px-major
  #pragma unroll
  for (int k = 0; k < 5; ++k){
    int idx = k*512 + t;                      // 2240 uint4 = 560 px x 4 parts
    if (idx < 2240){
      int part = idx & 3, pxi = idx >> 2;     // pxi: r*56 + c
      int r = pxi / 56, c = pxi - r*56;
      int hh = h0 - 1 + r;
      uint4 v = make_uint4(0,0,0,0);
      if ((unsigned)hh < 56u && mg[(hh>>3)*7 + (c>>3)] != 0.0f)  // masked px: exact 0
        v = *reinterpret_cast<const uint4*>(tg + (size_t)(hh*56 + c)*32 + part*8);
      *reinterpret_cast<uint4*>(&s[(r*58 + c + 1)*ICS + part*8]) = v;
    }
  }
  __syncthreads();
  float mkr[7];
  #pragma unroll
  for (int i = 0; i < 7; ++i) mkr[i] = mk[i];

  // ---------------- conv2 compute (reads s only) ----------------
  const int oct = wave & 1, rq = wave >> 1;        // oct 0..1, row-quarter 0..3
  floatx4 acc[7] = {};
  {
    const U16* wg = w2t + g*9*32*32;               // bf16 [tap][oc][ic]
    #pragma unroll
    for (int kh = 0; kh < 3; ++kh){
      const int lr = rq*2 + (l15 >> 3) + kh;       // 0..9
      #pragma unroll
      for (int kw = 0; kw < 3; ++kw){
        int tap = kh*3 + kw;
        short8 a0 = *reinterpret_cast<const short8*>(wg + (tap*32 + oct*16 + l15)*32 + quad*8);
        #pragma unroll
        for (int pxt = 0; pxt < 7; ++pxt){
          if (mkr[pxt] == 0.0f) continue;          // masked cell: acc stays 0 (exact)
          int cslot = pxt*8 + (l15 & 7) + kw;      // (col + 1) + (kw-1), 0..57
          short8 bfr = *reinterpret_cast<const short8*>(
              &s[(lr*58 + cslot)*ICS + quad*8]);   // ds_read_b128
          acc[pxt] = __builtin_amdgcn_mfma_f32_16x16x32_bf16(a0, bfr, acc[pxt], 0,0,0);
        }
      }
    }
  }
  __syncthreads();   // all reads of s done; safe to overwrite (t2s alias)

  // ---------------- conv2 epilogue -> t2s (px-major) ----------------
  {
    const int pr = rq*2 + (l15 >> 3);
    const float* scp = bn + 256 + g*32 + oct*16 + quad*4;
    const float* shp = bn + 384 + g*32 + oct*16 + quad*4;
    #pragma unroll
    for (int pxt = 0; pxt < 7; ++pxt){
      float m = mkr[pxt];
      U16 y[4];
      #pragma unroll
      for (int reg = 0; reg < 4; ++reg)
        y[reg] = f2b(fmaxf(scp[reg]*acc[pxt][reg] + shp[reg], 0.0f) * m);  // masked: 0
      int px = pr*56 + pxt*8 + (l15 & 7);
      *reinterpret_cast<uint2*>(&t2s[px*ICS + oct*16 + quad*4]) =
          make_uint2((U32)y[0] | ((U32)y[1]<<16), (U32)y[2] | ((U32)y[3]<<16));
    }
  }
  __syncthreads();

  // ---------------- conv3 + residual -> out ----------------
  {
    short8 afr = pack8(w3 + (size_t)(g*128 + wave*16 + l15)*32 + quad*8);  // fp32 [oc][ic32]
    const float* scp = bn + 512 + g*128 + wave*16 + quad*4;
    const float* shp = bn + 1024 + g*128 + wave*16 + quad*4;
    const float* xg = x + (size_t)(b*512 + g*128)*HW + h0*56;
    float* og = out + (size_t)(b*512 + g*128)*HW + h0*56;
    #pragma unroll
    for (int tt = 0; tt < 28; ++tt){
      int px = tt*16 + l15;
      short8 bfr = *reinterpret_cast<const short8*>(&t2s[px*ICS + quad*8]);  // b128
      floatx4 acc3 = {};
      acc3 = __builtin_amdgcn_mfma_f32_16x16x32_bf16(afr, bfr, acc3, 0,0,0);
      #pragma unroll
      for (int reg = 0; reg < 4; ++reg){
        size_t o2 = (size_t)(wave*16 + quad*4 + reg)*HW + px;
        float xr = __builtin_nontemporal_load(&xg[o2]);       // x: last use
        __builtin_nontemporal_store(
            fmaxf(scp[reg]*acc3[reg] + shp[reg] + xr, 0.0f), &og[o2]);  // out: never re-read
      }
    }
  }
}

// ---------------------------------------------------------------------------
extern "C" void kernel_launch(void* const* d_in, const int* in_sizes, int n_in,
                              void* d_out, int out_size, void* d_ws, size_t ws_size,
                              hipStream_t stream){
  const float* x    = (const float*)d_in[0];
  const float* mask = (const float*)d_in[1];
  const float* w1   = (const float*)d_in[2];
  const float* g1   = (const float*)d_in[3];
  const float* b1   = (const float*)d_in[4];
  const float* m1   = (const float*)d_in[5];
  const float* v1   = (const float*)d_in[6];
  const float* w2   = (const float*)d_in[7];
  const float* g2   = (const float*)d_in[8];
  const float* b2   = (const float*)d_in[9];
  const float* m2   = (const float*)d_in[10];
  const float* v2   = (const float*)d_in[11];
  const float* w3   = (const float*)d_in[12];
  const float* g3   = (const float*)d_in[13];
  const float* b3   = (const float*)d_in[14];
  const float* m3   = (const float*)d_in[15];
  const float* v3   = (const float*)d_in[16];

  char* ws = (char*)d_ws;
  U16*   w2t = (U16*)ws;                               //      0 .. 73,728
  float* bn  = (float*)(ws + 73728);                   // 73,728 .. 79,872
  U16*   t1  = (U16*)(ws + 79872);                     // 12,845,056 B (px-major)

  dim3 grid1(8, 4, 16);  // x=7: pre block (w2t+bn); x<7: 8-row strips
  k_conv1<<<grid1, 512, 0, stream>>>(x, mask, w1, w2,
      g1,b1,m1,v1, g2,b2,m2,v2, g3,b3,m3,v3, w2t, bn, t1);
  dim3 grid2(7, 4, 16);  // (8-row strip, group, batch)
  k_conv23<<<grid2, 512, 0, stream>>>(t1, mask, w2t, w3, bn, x, (float*)d_out);
}